// Round 1
// baseline (352.552 us; speedup 1.0000x reference)
//
#include <hip/hip_runtime.h>

// Problem constants (match reference)
#define Bdim 4
#define Cdim 32
#define Hdim 512
#define Wdim 512
#define HWdim (Hdim * Wdim)

typedef __attribute__((ext_vector_type(4))) float    f32x4;
typedef __attribute__((ext_vector_type(2))) _Float16 f16x2;
typedef __attribute__((ext_vector_type(4))) _Float16 f16x4;
typedef __attribute__((ext_vector_type(8))) _Float16 f16x8;

// ---------------------------------------------------------------------------
// Kernel A: transpose x [B][C][H][W] (fp32) -> ws NHWC [B][H][W][C] (fp16)
// One block: (b, h) fixed, 128-wide w strip, all 32 c.
// float4 global loads, f32x4 LDS stores (pad 132 -> 16B-aligned, conflict-free),
// f16x8 (16B) NHWC stores, 2 per thread (32B contiguous each).
// ---------------------------------------------------------------------------
__global__ __launch_bounds__(256) void transpose_nhwc_half_kernel(
    const float* __restrict__ x, _Float16* __restrict__ ws)
{
    __shared__ float lds[Cdim * 132];   // 32 x 132 floats = 16896 B

    const int idx = blockIdx.x;               // B*H*4 = 8192 blocks
    const int tw  = idx & 3;                  // W/128 = 4 strips
    const int h   = (idx >> 2) & (Hdim - 1);
    const int b   = idx >> 11;
    const int w0  = tw * 128;
    const int t   = threadIdx.x;

    // 32c x 128w = 1024 float4s, 4 per thread. Issue all loads first (MLP).
    f32x4 r[4];
    #pragma unroll
    for (int i = 0; i < 4; ++i) {
        const int f4 = i * 256 + t;           // 0..1023
        const int c  = f4 >> 5;               // 32 float4 per row
        const int w4 = f4 & 31;
        r[i] = *(const f32x4*)(x + (((size_t)b * Cdim + c) * Hdim + h) * Wdim + w0 + w4 * 4);
    }
    #pragma unroll
    for (int i = 0; i < 4; ++i) {
        const int f4 = i * 256 + t;
        *(f32x4*)(lds + (f4 >> 5) * 132 + (f4 & 31) * 4) = r[i];
    }
    __syncthreads();

    // output block = 4096 halves contiguous; thread t writes halves [t*16, t*16+16)
    const size_t base = (((size_t)b * Hdim + h) * Wdim + w0) * Cdim;
    const int w_ = t >> 1;                    // local w (0..127)
    const int c0 = (t & 1) * 16;              // first channel (0 or 16)
    f16x8 v0, v1;
    #pragma unroll
    for (int k = 0; k < 8; ++k) v0[k] = (_Float16)lds[(c0 + k) * 132 + w_];
    #pragma unroll
    for (int k = 0; k < 8; ++k) v1[k] = (_Float16)lds[(c0 + 8 + k) * 132 + w_];
    *(f16x8*)(ws + base + (size_t)w_ * Cdim + c0)     = v0;   // 16B store
    *(f16x8*)(ws + base + (size_t)w_ * Cdim + c0 + 8) = v1;   // 16B store
}

// ---------------------------------------------------------------------------
// Kernel B: gather from NHWC fp16 ws + residual -> out (NCHW fp32)
// Block = 256 consecutive pixels of one row (b, h, w0..w0+255).
// Phase 1: per-pixel flow math -> LDS (NHWC half offsets, fp32 weights)
// Phase 2: 4 lanes per pixel, 8 channels each (f16x8 = 16B per corner load;
//          4 lanes x 16B = one full 64B line per corner). Two half-passes;
//          all 8 corner loads of pass A + ALL 32 residual loads issued before
//          any math so the streaming residual read overlaps the LLC gathers.
// Phase 3: read s_buf row (f16x4), add register-resident residual, coalesced
//          NCHW nontemporal stores.
// ---------------------------------------------------------------------------
__global__ __launch_bounds__(256) void gather_nhwc_half_kernel(
    const _Float16* __restrict__ ws,
    const float* __restrict__ flow,
    const float* __restrict__ residual,
    float* __restrict__ out)
{
    __shared__ int      s_off[4][256];
    __shared__ float    s_wt[4][256];
    __shared__ _Float16 s_buf[256 * 36];   // [pix][c], stride 36 halves (72B rows, 8B-aligned lanes)

    const int idx = blockIdx.x;                 // 4096 blocks
    const int b   = idx >> 10;
    const int h   = (idx >> 1) & (Hdim - 1);
    const int w0  = (idx & 1) << 8;
    const int t   = threadIdx.x;

    // ---- Phase 1: per-pixel sampling math (numerics identical to prior) ----
    {
        const int w = w0 + t;
        const int pixg = h * Wdim + w;
        const float fx = flow[((size_t)b * 2 + 0) * HWdim + pixg];
        const float fy = flow[((size_t)b * 2 + 1) * HWdim + pixg];

        float gx = ((float)w + 0.5f) * (2.0f / (float)Wdim) - 1.0f + fx;
        float gy = ((float)h + 0.5f) * (2.0f / (float)Hdim) - 1.0f + fy;

        float tm = fmodf(gx + 1.0f, 2.0f);
        if (tm < 0.0f) tm += 2.0f;
        gx = tm - 1.0f;

        const float real_x = (gx + 1.0f) * ((float)Wdim * 0.5f) - 0.5f;
        const float real_y = (gy + 1.0f) * ((float)Hdim * 0.5f) - 0.5f;

        const float x0f = floorf(real_x);
        const float y0f = floorf(real_y);
        const float dx = real_x - x0f;
        const float dy = real_y - y0f;

        const int ix0 = (int)x0f;
        const int iy0 = (int)y0f;
        const int ix1 = ix0 + 1;
        const int iy1 = iy0 + 1;

        const bool vx0 = (ix0 >= 0) && (ix0 < Wdim);
        const bool vx1 = (ix1 >= 0) && (ix1 < Wdim);
        const bool vy0 = (iy0 >= 0) && (iy0 < Hdim);
        const bool vy1 = (iy1 >= 0) && (iy1 < Hdim);

        const int cx0 = min(max(ix0, 0), Wdim - 1);
        const int cx1 = min(max(ix1, 0), Wdim - 1);
        const int cy0 = min(max(iy0, 0), Hdim - 1);
        const int cy1 = min(max(iy1, 0), Hdim - 1);

        float w_tl = (1.0f - dx) * (1.0f - dy);
        float w_tr = dx * (1.0f - dy);
        float w_bl = (1.0f - dx) * dy;
        float w_br = dx * dy;
        if (!(vx0 && vy0)) w_tl = 0.0f;
        if (!(vx1 && vy0)) w_tr = 0.0f;
        if (!(vx0 && vy1)) w_bl = 0.0f;
        if (!(vx1 && vy1)) w_br = 0.0f;

        s_off[0][t] = (cy0 * Wdim + cx0) * Cdim;   // offsets in halves
        s_off[1][t] = (cy0 * Wdim + cx1) * Cdim;
        s_off[2][t] = (cy1 * Wdim + cx0) * Cdim;
        s_off[3][t] = (cy1 * Wdim + cx1) * Cdim;
        s_wt[0][t] = w_tl;
        s_wt[1][t] = w_tr;
        s_wt[2][t] = w_bl;
        s_wt[3][t] = w_br;
    }
    __syncthreads();

    // ---- Phase 2: coalesced channel-major gather, deep MLP ----
    const int ci = t & 3;                      // channel oct: channels 8ci..8ci+7
    const int c0 = ci * 8;
    const int p  = t >> 2;                     // 0..63 pixel slot
    const _Float16* xb = ws + (size_t)b * (size_t)HWdim * Cdim + c0;
    const size_t pbase = (size_t)h * Wdim + w0 + t;
    const float* rb = residual + (size_t)b * Cdim * (size_t)HWdim + pbase;

    float rres[Cdim];                          // residual for this thread's phase-3 pixel

    // pass A: pixels p, 64+p
    int   oa[2][4]; float wa[2][4]; f16x8 va[2][4];
    #pragma unroll
    for (int j = 0; j < 2; ++j) {
        const int pix = j * 64 + p;
        #pragma unroll
        for (int k = 0; k < 4; ++k) { oa[j][k] = s_off[k][pix]; wa[j][k] = s_wt[k][pix]; }
    }
    #pragma unroll
    for (int j = 0; j < 2; ++j) {
        #pragma unroll
        for (int k = 0; k < 4; ++k) va[j][k] = *(const f16x8*)(xb + (size_t)oa[j][k]);  // 16B loads
    }
    // residual prefetch: independent stream, stays in flight under pass-A math
    #pragma unroll
    for (int c = 0; c < Cdim; ++c) rres[c] = __builtin_nontemporal_load(rb + (size_t)c * HWdim);

    #pragma unroll
    for (int j = 0; j < 2; ++j) {
        const int pix = j * 64 + p;
        float acc[8];
        #pragma unroll
        for (int e = 0; e < 8; ++e)
            acc[e] = wa[j][0] * (float)va[j][0][e] + wa[j][1] * (float)va[j][1][e]
                   + wa[j][2] * (float)va[j][2][e] + wa[j][3] * (float)va[j][3][e];
        f16x4 h0, h1;
        #pragma unroll
        for (int e = 0; e < 4; ++e) { h0[e] = (_Float16)acc[e]; h1[e] = (_Float16)acc[4 + e]; }
        *(f16x4*)(s_buf + pix * 36 + c0)     = h0;   // 8B LDS stores
        *(f16x4*)(s_buf + pix * 36 + c0 + 4) = h1;
    }

    // pass B: pixels 128+p, 192+p
    int   ob[2][4]; float wb[2][4]; f16x8 vb[2][4];
    #pragma unroll
    for (int j = 0; j < 2; ++j) {
        const int pix = 128 + j * 64 + p;
        #pragma unroll
        for (int k = 0; k < 4; ++k) { ob[j][k] = s_off[k][pix]; wb[j][k] = s_wt[k][pix]; }
    }
    #pragma unroll
    for (int j = 0; j < 2; ++j) {
        #pragma unroll
        for (int k = 0; k < 4; ++k) vb[j][k] = *(const f16x8*)(xb + (size_t)ob[j][k]);
    }
    #pragma unroll
    for (int j = 0; j < 2; ++j) {
        const int pix = 128 + j * 64 + p;
        float acc[8];
        #pragma unroll
        for (int e = 0; e < 8; ++e)
            acc[e] = wb[j][0] * (float)vb[j][0][e] + wb[j][1] * (float)vb[j][1][e]
                   + wb[j][2] * (float)vb[j][2][e] + wb[j][3] * (float)vb[j][3][e];
        f16x4 h0, h1;
        #pragma unroll
        for (int e = 0; e < 4; ++e) { h0[e] = (_Float16)acc[e]; h1[e] = (_Float16)acc[4 + e]; }
        *(f16x4*)(s_buf + pix * 36 + c0)     = h0;
        *(f16x4*)(s_buf + pix * 36 + c0 + 4) = h1;
    }
    __syncthreads();

    // ---- Phase 3: coalesced NCHW store + register-resident residual ----
    {
        const size_t obase = (size_t)b * Cdim * (size_t)HWdim + pbase;
        const _Float16* row = s_buf + t * 36;
        #pragma unroll
        for (int cc = 0; cc < Cdim; cc += 4) {
            const f16x4 v = *(const f16x4*)(row + cc);   // 8B LDS read
            #pragma unroll
            for (int e = 0; e < 4; ++e)
                __builtin_nontemporal_store((float)v[e] + rres[cc + e],
                                            out + obase + (size_t)(cc + e) * HWdim);
        }
    }
}

// ---------------------------------------------------------------------------
// Fallback (R1 kernel) if workspace is too small for the NHWC fp16 buffer
// ---------------------------------------------------------------------------
__global__ __launch_bounds__(256) void warp_add_kernel(
    const float* __restrict__ x,
    const float* __restrict__ flow,
    const float* __restrict__ residual,
    float* __restrict__ out)
{
    int tid = blockIdx.x * blockDim.x + threadIdx.x;
    int w = tid & (Wdim - 1);
    int h = (tid >> 9) & (Hdim - 1);
    int b = tid >> 18;

    const float fx = flow[((size_t)b * 2 + 0) * HWdim + h * Wdim + w];
    const float fy = flow[((size_t)b * 2 + 1) * HWdim + h * Wdim + w];

    float gx = ((float)w + 0.5f) * (2.0f / (float)Wdim) - 1.0f + fx;
    float gy = ((float)h + 0.5f) * (2.0f / (float)Hdim) - 1.0f + fy;
    {
        float t2 = fmodf(gx + 1.0f, 2.0f);
        if (t2 < 0.0f) t2 += 2.0f;
        gx = t2 - 1.0f;
    }
    const float real_x = (gx + 1.0f) * ((float)Wdim * 0.5f) - 0.5f;
    const float real_y = (gy + 1.0f) * ((float)Hdim * 0.5f) - 0.5f;
    const float x0f = floorf(real_x);
    const float y0f = floorf(real_y);
    const float dx = real_x - x0f;
    const float dy = real_y - y0f;
    const int ix0 = (int)x0f, iy0 = (int)y0f;
    const int ix1 = ix0 + 1,  iy1 = iy0 + 1;
    const bool vx0 = (ix0 >= 0) && (ix0 < Wdim);
    const bool vx1 = (ix1 >= 0) && (ix1 < Wdim);
    const bool vy0 = (iy0 >= 0) && (iy0 < Hdim);
    const bool vy1 = (iy1 >= 0) && (iy1 < Hdim);
    const int cx0 = min(max(ix0, 0), Wdim - 1);
    const int cx1 = min(max(ix1, 0), Wdim - 1);
    const int cy0 = min(max(iy0, 0), Hdim - 1);
    const int cy1 = min(max(iy1, 0), Hdim - 1);
    float w_tl = (1.0f - dx) * (1.0f - dy);
    float w_tr = dx * (1.0f - dy);
    float w_bl = (1.0f - dx) * dy;
    float w_br = dx * dy;
    if (!(vx0 && vy0)) w_tl = 0.0f;
    if (!(vx1 && vy0)) w_tr = 0.0f;
    if (!(vx0 && vy1)) w_bl = 0.0f;
    if (!(vx1 && vy1)) w_br = 0.0f;
    const int off_tl = cy0 * Wdim + cx0;
    const int off_tr = cy0 * Wdim + cx1;
    const int off_bl = cy1 * Wdim + cx0;
    const int off_br = cy1 * Wdim + cx1;
    const size_t base = (size_t)b * Cdim * HWdim;
    const int    pix  = h * Wdim + w;
    const float* xb = x + base;
    const float* rbp = residual + base + pix;
    float*       ob = out + base + pix;
    #pragma unroll 8
    for (int c = 0; c < Cdim; ++c) {
        const float* xc = xb + (size_t)c * HWdim;
        float v = w_tl * xc[off_tl] + w_tr * xc[off_tr]
                + w_bl * xc[off_bl] + w_br * xc[off_br]
                + rbp[(size_t)c * HWdim];
        ob[(size_t)c * HWdim] = v;
    }
}

extern "C" void kernel_launch(void* const* d_in, const int* in_sizes, int n_in,
                              void* d_out, int out_size, void* d_ws, size_t ws_size,
                              hipStream_t stream) {
    const float* x        = (const float*)d_in[0];
    const float* flow     = (const float*)d_in[1];
    const float* residual = (const float*)d_in[2];
    float* out            = (float*)d_out;

    const size_t ws_needed = (size_t)Bdim * Cdim * HWdim * sizeof(_Float16); // 64 MiB

    if (ws_size >= ws_needed) {
        _Float16* ws = (_Float16*)d_ws;
        transpose_nhwc_half_kernel<<<Bdim * Hdim * (Wdim / 128), 256, 0, stream>>>(x, ws);
        gather_nhwc_half_kernel<<<Bdim * Hdim * Wdim / 256, 256, 0, stream>>>(ws, flow, residual, out);
    } else {
        const int total = Bdim * Hdim * Wdim;
        warp_add_kernel<<<total / 256, 256, 0, stream>>>(x, flow, residual, out);
    }
}